// Round 7
// baseline (303.410 us; speedup 1.0000x reference)
//
#include <hip/hip_runtime.h>
#include <stdint.h>

typedef __attribute__((ext_vector_type(8))) short bf16x8;
typedef __attribute__((ext_vector_type(4))) float f32x4;

#define B_ROWS 131072
#define BM 32
#define NT 4             // tiles per block, pipelined
#define GRID 1024        // 1024 * 4 * 32 = 131072 rows
#define ZP 456           // z row pitch in bf16 (448 + 8 pad)
#define AP 136           // a1/a2 row pitch in bf16 (128 + 8 pad)

#define Z_OFF    0
#define A1_OFF   (BM * ZP * 2)            // 29184
#define A2_OFF   (A1_OFF + BM * AP * 2)   // 37888
#define LSUM_OFF (A2_OFF + BM * AP * 2)   // 46592
#define LDS_TOTAL (LSUM_OFF + 4 * BM * 4) // 47104 -> 3 blocks/CU

// packed weight fragment offsets (uint4 units)
#define W1P_OFF 0      // 8 nt * 14 kt * 64
#define W2P_OFF 7168   // 8 * 4 * 64
#define W3P_OFF 9216   // 16 * 4 * 64

__device__ inline uint16_t f2bf(float x) {
  uint32_t u = __float_as_uint(x);
  u += 0x7fffu + ((u >> 16) & 1u);   // RNE
  return (uint16_t)(u >> 16);
}

__device__ inline float tanh_fast(float x) {
  x = fminf(fmaxf(x, -15.f), 15.f);
  float e = __expf(2.f * x);
  return (e - 1.f) / (e + 1.f);
}

__global__ void prepack_kernel(const float* __restrict__ W1,
                               const float* __restrict__ W2,
                               const float* __restrict__ W3,
                               uint4* __restrict__ wp) {
  int tid = blockIdx.x * 256 + threadIdx.x;
  if (tid >= 13312) return;
  int l = tid & 63, f = tid >> 6;
  const float* W; int N, kt, nt;
  if (f < 112)      { W = W1; N = 128; int ff = f;       nt = ff / 14; kt = ff - nt * 14; }
  else if (f < 144) { W = W2; N = 128; int ff = f - 112; nt = ff >> 2; kt = ff & 3; }
  else              { W = W3; N = 256; int ff = f - 144; nt = ff >> 2; kt = ff & 3; }
  int k0  = kt * 32 + (l >> 4) * 8;
  int col = nt * 16 + (l & 15);
  uint16_t v[8];
#pragma unroll
  for (int j = 0; j < 8; j++) v[j] = f2bf(W[(size_t)(k0 + j) * N + col]);
  uint4 o;
  o.x = (uint32_t)v[0] | ((uint32_t)v[1] << 16);
  o.y = (uint32_t)v[2] | ((uint32_t)v[3] << 16);
  o.z = (uint32_t)v[4] | ((uint32_t)v[5] << 16);
  o.w = (uint32_t)v[6] | ((uint32_t)v[7] << 16);
  wp[tid] = o;
}

// convert held f32 regs -> bf16 and write into z buffer
__device__ inline void stage_write(uint16_t* zn, int t,
                                   const float4* xr, const float4* hr) {
#pragma unroll
  for (int k = 0; k < 8; k++) {
    int idx = t + k * 256;
    int row = idx >> 6, c4 = idx & 63;
    uint32_t p = (uint32_t)f2bf(xr[k].x) | ((uint32_t)f2bf(xr[k].z) << 16);
    *(uint32_t*)&zn[row * ZP + c4 * 2] = p;
  }
#pragma unroll
  for (int k = 0; k < 10; k++) {
    int idx = t + k * 256;
    int row = idx / 80, c4 = idx - row * 80;
    uint2 p;
    p.x = (uint32_t)f2bf(hr[k].x) | ((uint32_t)f2bf(hr[k].y) << 16);
    p.y = (uint32_t)f2bf(hr[k].z) | ((uint32_t)f2bf(hr[k].w) << 16);
    *(uint2*)&zn[row * ZP + 128 + c4 * 4] = p;
  }
}

__global__ __launch_bounds__(256, 3) void fused_kernel(
    const float* __restrict__ x, const float* __restrict__ h,
    const float* __restrict__ b1, const float* __restrict__ b2,
    const float* __restrict__ b3, const uint4* __restrict__ wp,
    float* __restrict__ y, float* __restrict__ ldet) {
  extern __shared__ uint8_t smem[];
  uint16_t* zs   = (uint16_t*)(smem + Z_OFF);    // [32][456] single buffer
  uint16_t* a1   = (uint16_t*)(smem + A1_OFF);   // [32][136]
  uint16_t* a2   = (uint16_t*)(smem + A2_OFF);   // [32][136] own region, NO aliases
  float*    lsum = (float*)(smem + LSUM_OFF);    // 128 f32

  const int t = threadIdx.x;
  const int wid = t >> 6, l = t & 63;
  const int lr = l & 15, lq = l >> 4;
  const int tile0 = blockIdx.x * NT;

  // ---- prologue: stage tile 0
  {
    const int m0 = tile0 * BM;
    float4 xr[8], hr[10];
    const float4* xg = (const float4*)(x + (size_t)m0 * 256);
#pragma unroll
    for (int k = 0; k < 8; k++) xr[k] = xg[t + k * 256];
    const float4* hg = (const float4*)(h + (size_t)m0 * 320);
#pragma unroll
    for (int k = 0; k < 10; k++) hr[k] = hg[t + k * 256];
    stage_write(zs, t, xr, hr);
  }
  __syncthreads();

  for (int it = 0; it < NT; ++it) {
    const int m0 = (tile0 + it) * BM;
    const bool pf = (it + 1 < NT);

    // ---- (1) issue next tile's global loads; consumed right after barrier α.
    //      Held across GEMM1 only (~72 VGPR), HBM latency hides under G1.
    float4 xr[8], hr[10];
    if (pf) {
      const float4* xg = (const float4*)(x + (size_t)(m0 + BM) * 256);
#pragma unroll
      for (int k = 0; k < 8; k++) xr[k] = xg[t + k * 256];
      const float4* hg = (const float4*)(h + (size_t)(m0 + BM) * 320);
#pragma unroll
      for (int k = 0; k < 10; k++) hr[k] = hg[t + k * 256];
    }

    // ---- (2) GEMM1: a1 = relu(z @ W1 + b1); wave owns 32 cols
    {
      f32x4 acc[2][2] = {};
#pragma unroll 2
      for (int kt = 0; kt < 14; kt++) {
        bf16x8 afr[2];
#pragma unroll
        for (int mi = 0; mi < 2; mi++)
          afr[mi] = *(const bf16x8*)&zs[(mi * 16 + lr) * ZP + kt * 32 + lq * 8];
        bf16x8 bfr[2];
#pragma unroll
        for (int nj = 0; nj < 2; nj++)
          bfr[nj] = *(const bf16x8*)&wp[W1P_OFF + ((wid * 2 + nj) * 14 + kt) * 64 + l];
#pragma unroll
        for (int mi = 0; mi < 2; mi++)
#pragma unroll
          for (int nj = 0; nj < 2; nj++)
            acc[mi][nj] = __builtin_amdgcn_mfma_f32_16x16x32_bf16(afr[mi], bfr[nj], acc[mi][nj], 0, 0, 0);
      }
#pragma unroll
      for (int mi = 0; mi < 2; mi++)
#pragma unroll
        for (int nj = 0; nj < 2; nj++) {
          int col = wid * 32 + nj * 16 + lr;
          float bv = b1[col];
#pragma unroll
          for (int r = 0; r < 4; r++)
            a1[(mi * 16 + lq * 4 + r) * AP + col] = f2bf(fmaxf(acc[mi][nj][r] + bv, 0.f));
        }
    }
    __syncthreads();   // α: a1 visible; z dead

    // ---- (4) stage next tile's z (z region free now); frees the 72 regs
    if (pf) stage_write(zs, t, xr, hr);

    // ---- (5) GEMM2: a2 = relu(a1 @ W2 + b2)  (a2 region disjoint from a1, z)
    {
      f32x4 acc[2][2] = {};
#pragma unroll
      for (int kt = 0; kt < 4; kt++) {
        bf16x8 afr[2];
#pragma unroll
        for (int mi = 0; mi < 2; mi++)
          afr[mi] = *(const bf16x8*)&a1[(mi * 16 + lr) * AP + kt * 32 + lq * 8];
        bf16x8 bfr[2];
#pragma unroll
        for (int nj = 0; nj < 2; nj++)
          bfr[nj] = *(const bf16x8*)&wp[W2P_OFF + ((wid * 2 + nj) * 4 + kt) * 64 + l];
#pragma unroll
        for (int mi = 0; mi < 2; mi++)
#pragma unroll
          for (int nj = 0; nj < 2; nj++)
            acc[mi][nj] = __builtin_amdgcn_mfma_f32_16x16x32_bf16(afr[mi], bfr[nj], acc[mi][nj], 0, 0, 0);
      }
#pragma unroll
      for (int mi = 0; mi < 2; mi++)
#pragma unroll
        for (int nj = 0; nj < 2; nj++) {
          int col = wid * 32 + nj * 16 + lr;
          float bv = b2[col];
#pragma unroll
          for (int r = 0; r < 4; r++)
            a2[(mi * 16 + lq * 4 + r) * AP + col] = f2bf(fmaxf(acc[mi][nj][r] + bv, 0.f));
        }
    }
    __syncthreads();   // β: a2 + z(next) visible

    // ---- (7) epilogue x prefetch (L2/L3-hot), GEMM3, epilogue
    float2 xv[2][2][4];
#pragma unroll
    for (int mi = 0; mi < 2; mi++)
#pragma unroll
      for (int nj = 0; nj < 2; nj++) {
        int colc = wid * 32 + nj * 16 + lr;
#pragma unroll
        for (int r = 0; r < 4; r++) {
          int grow = m0 + mi * 16 + lq * 4 + r;
          xv[mi][nj][r] = *(const float2*)(x + (size_t)grow * 256 + 2 * colc);
        }
      }

    f32x4 acc3[2][4] = {};
#pragma unroll
    for (int kt = 0; kt < 4; kt++) {
      bf16x8 afr[2];
#pragma unroll
      for (int mi = 0; mi < 2; mi++)
        afr[mi] = *(const bf16x8*)&a2[(mi * 16 + lr) * AP + kt * 32 + lq * 8];
      bf16x8 bfr[4];
#pragma unroll
      for (int nj = 0; nj < 2; nj++) {
        bfr[nj]     = *(const bf16x8*)&wp[W3P_OFF + ((wid * 2 + nj) * 4 + kt) * 64 + l];
        bfr[nj + 2] = *(const bf16x8*)&wp[W3P_OFF + ((8 + wid * 2 + nj) * 4 + kt) * 64 + l];
      }
#pragma unroll
      for (int mi = 0; mi < 2; mi++)
#pragma unroll
        for (int nj = 0; nj < 4; nj++)
          acc3[mi][nj] = __builtin_amdgcn_mfma_f32_16x16x32_bf16(afr[mi], bfr[nj], acc3[mi][nj], 0, 0, 0);
    }

    float lp[2][4];
#pragma unroll
    for (int mi = 0; mi < 2; mi++)
#pragma unroll
      for (int r = 0; r < 4; r++) lp[mi][r] = 0.f;

#pragma unroll
    for (int mi = 0; mi < 2; mi++)
#pragma unroll
      for (int nj = 0; nj < 2; nj++) {
        int colc = wid * 32 + nj * 16 + lr;
        float bs = b3[colc];
        float bt = b3[128 + colc];
#pragma unroll
        for (int r = 0; r < 4; r++) {
          int grow = m0 + mi * 16 + lq * 4 + r;
          float sv = tanh_fast(acc3[mi][nj][r] + bs);
          float tv = acc3[mi][nj + 2][r] + bt;
          lp[mi][r] += sv;
          float2 o;
          o.x = xv[mi][nj][r].x;                 // exact pass-through
          o.y = xv[mi][nj][r].y * __expf(sv) + tv;
          *(float2*)(y + (size_t)grow * 256 + 2 * colc) = o;
        }
      }

#pragma unroll
    for (int mi = 0; mi < 2; mi++)
#pragma unroll
      for (int r = 0; r < 4; r++) {
        float v = lp[mi][r];
        v += __shfl_xor(v, 1);
        v += __shfl_xor(v, 2);
        v += __shfl_xor(v, 4);
        v += __shfl_xor(v, 8);
        if (lr == 0) lsum[wid * BM + mi * 16 + lq * 4 + r] = v;
      }
    __syncthreads();   // γ: lsum visible; a1/a2 reads done
    if (t < BM)
      ldet[m0 + t] = lsum[t] + lsum[BM + t] + lsum[2 * BM + t] + lsum[3 * BM + t];
  }
}

extern "C" void kernel_launch(void* const* d_in, const int* in_sizes, int n_in,
                              void* d_out, int out_size, void* d_ws, size_t ws_size,
                              hipStream_t stream) {
  const float* x  = (const float*)d_in[0];
  const float* h  = (const float*)d_in[1];
  const float* W1 = (const float*)d_in[2];
  const float* b1 = (const float*)d_in[3];
  const float* W2 = (const float*)d_in[4];
  const float* b2 = (const float*)d_in[5];
  const float* W3 = (const float*)d_in[6];
  const float* b3 = (const float*)d_in[7];
  float* y    = (float*)d_out;
  float* ldet = y + (size_t)B_ROWS * 256;
  uint4* wp   = (uint4*)d_ws;

  prepack_kernel<<<52, 256, 0, stream>>>(W1, W2, W3, wp);

  (void)hipFuncSetAttribute((const void*)fused_kernel,
                            hipFuncAttributeMaxDynamicSharedMemorySize, LDS_TOTAL);
  fused_kernel<<<GRID, 256, LDS_TOTAL, stream>>>(x, h, b1, b2, b3, wp, y, ldet);
}

// Round 8
// 127.114 us; speedup vs baseline: 2.3869x; 2.3869x over previous
//
#include <hip/hip_runtime.h>
#include <hip/hip_bf16.h>
#include <stdint.h>

typedef __attribute__((ext_vector_type(8))) short bf16x8;
typedef __attribute__((ext_vector_type(4))) float f32x4;

#define B_ROWS 131072
#define BM 16
#define XP 268    // x f32 row pitch (256 + 12 pad; 12 banks offset/row -> ~2-way max)
#define ZHP 328   // h bf16 row pitch (320 + 8 pad)
#define AP 136    // a1/a2 bf16 row pitch (128 + 8 pad)

#define XS_BYTES (BM * XP * 4)             // 17152
#define ZH_OFF   XS_BYTES                  // 17152
#define ZH_BYTES (BM * ZHP * 2)            // 10496
#define A1_OFF   (ZH_OFF + ZH_BYTES)       // 27648
#define A1_BYTES (BM * AP * 2)             // 4352
#define LSUM_OFF (A1_OFF + A1_BYTES)       // 32000
#define LDS_TOTAL (LSUM_OFF + 64 * 4)      // 32256 -> 5 blocks/CU (161280 <= 163840)

// packed weight fragment offsets (uint4 units)
#define W1P_OFF 0      // 8 nt * 14 kt * 64
#define W2P_OFF 7168   // 8 * 4 * 64
#define W3P_OFF 9216   // 16 * 4 * 64

__device__ inline uint16_t f2bf(float x) {
  uint32_t u = __float_as_uint(x);
  u += 0x7fffu + ((u >> 16) & 1u);   // RNE
  return (uint16_t)(u >> 16);
}

__device__ inline float tanh_fast(float x) {
  x = fminf(fmaxf(x, -15.f), 15.f);
  float e = __expf(2.f * x);
  return (e - 1.f) / (e + 1.f);
}

__global__ void prepack_kernel(const float* __restrict__ W1,
                               const float* __restrict__ W2,
                               const float* __restrict__ W3,
                               uint4* __restrict__ wp) {
  int tid = blockIdx.x * 256 + threadIdx.x;
  if (tid >= 13312) return;
  int l = tid & 63, f = tid >> 6;
  const float* W; int N, kt, nt;
  if (f < 112)      { W = W1; N = 128; int ff = f;       nt = ff / 14; kt = ff - nt * 14; }
  else if (f < 144) { W = W2; N = 128; int ff = f - 112; nt = ff >> 2; kt = ff & 3; }
  else              { W = W3; N = 256; int ff = f - 144; nt = ff >> 2; kt = ff & 3; }
  int k0  = kt * 32 + (l >> 4) * 8;
  int col = nt * 16 + (l & 15);
  uint16_t v[8];
#pragma unroll
  for (int j = 0; j < 8; j++) v[j] = f2bf(W[(size_t)(k0 + j) * N + col]);
  uint4 o;
  o.x = (uint32_t)v[0] | ((uint32_t)v[1] << 16);
  o.y = (uint32_t)v[2] | ((uint32_t)v[3] << 16);
  o.z = (uint32_t)v[4] | ((uint32_t)v[5] << 16);
  o.w = (uint32_t)v[6] | ((uint32_t)v[7] << 16);
  wp[tid] = o;
}

__global__ __launch_bounds__(256, 5) void fused_kernel(
    const float* __restrict__ x, const float* __restrict__ h,
    const float* __restrict__ b1, const float* __restrict__ b2,
    const float* __restrict__ b3, const uint4* __restrict__ wp,
    float* __restrict__ y, float* __restrict__ ldet) {
  extern __shared__ uint8_t smem[];
  float*    xs   = (float*)smem;                 // [16][268] f32, exact x rows
  uint16_t* zh   = (uint16_t*)(smem + ZH_OFF);   // [16][328] bf16, h part of z
  uint16_t* a1   = (uint16_t*)(smem + A1_OFF);   // [16][136] bf16
  uint16_t* a2   = zh;                           // alias: zh dead after GEMM1 (B1)
  float*    lsum = (float*)(smem + LSUM_OFF);    // 64 f32

  const int t  = threadIdx.x;
  const int m0 = blockIdx.x * BM;

  // ---- stage: x rows raw f32 -> xs (pure copy); h -> zh bf16
  {
    const float4* xg = (const float4*)(x + (size_t)m0 * 256);
#pragma unroll
    for (int k = 0; k < 4; k++) {
      int idx = t + k * 256;              // 0..1023 = 16 rows * 64 float4
      int row = idx >> 6, c4 = idx & 63;
      *(float4*)&xs[row * XP + c4 * 4] = xg[idx];
    }
    const float4* hg = (const float4*)(h + (size_t)m0 * 320);
#pragma unroll
    for (int k = 0; k < 5; k++) {
      int idx = t + k * 256;              // 0..1279 = 16 rows * 80 float4
      int row = idx / 80, c4 = idx - row * 80;
      float4 v = hg[idx];
      uint2 p;
      p.x = (uint32_t)f2bf(v.x) | ((uint32_t)f2bf(v.y) << 16);
      p.y = (uint32_t)f2bf(v.z) | ((uint32_t)f2bf(v.w) << 16);
      *(uint2*)&zh[row * ZHP + c4 * 4] = p;
    }
  }
  __syncthreads();   // B0

  const int wid = t >> 6, l = t & 63;
  const int lr = l & 15, lq = l >> 4;

  // ---- GEMM1: a1 = relu(z(16x448) @ W1 + b1); z = [x_even | h]
  {
    f32x4 acc[2] = {};
    // x-even part: kt 0..3, fragments built from f32 xs (stride-2) + cvt_pk
#pragma unroll
    for (int kt = 0; kt < 4; kt++) {
      int base = lr * XP + kt * 64 + lq * 16;   // f32 idx of x col 2*(kt*32+lq*8)
      float4 q0 = *(const float4*)&xs[base + 0];
      float4 q1 = *(const float4*)&xs[base + 4];
      float4 q2 = *(const float4*)&xs[base + 8];
      float4 q3 = *(const float4*)&xs[base + 12];
      union { bf16x8 v; __hip_bfloat162 h2[4]; } u;
      u.h2[0] = __float22bfloat162_rn(make_float2(q0.x, q0.z));
      u.h2[1] = __float22bfloat162_rn(make_float2(q1.x, q1.z));
      u.h2[2] = __float22bfloat162_rn(make_float2(q2.x, q2.z));
      u.h2[3] = __float22bfloat162_rn(make_float2(q3.x, q3.z));
      bf16x8 bfr0 = *(const bf16x8*)&wp[W1P_OFF + ((wid * 2 + 0) * 14 + kt) * 64 + l];
      bf16x8 bfr1 = *(const bf16x8*)&wp[W1P_OFF + ((wid * 2 + 1) * 14 + kt) * 64 + l];
      acc[0] = __builtin_amdgcn_mfma_f32_16x16x32_bf16(u.v, bfr0, acc[0], 0, 0, 0);
      acc[1] = __builtin_amdgcn_mfma_f32_16x16x32_bf16(u.v, bfr1, acc[1], 0, 0, 0);
    }
    // h part: kt 4..13, contiguous bf16 in zh
#pragma unroll 2
    for (int kt = 4; kt < 14; kt++) {
      bf16x8 afr = *(const bf16x8*)&zh[lr * ZHP + (kt - 4) * 32 + lq * 8];
      bf16x8 bfr0 = *(const bf16x8*)&wp[W1P_OFF + ((wid * 2 + 0) * 14 + kt) * 64 + l];
      bf16x8 bfr1 = *(const bf16x8*)&wp[W1P_OFF + ((wid * 2 + 1) * 14 + kt) * 64 + l];
      acc[0] = __builtin_amdgcn_mfma_f32_16x16x32_bf16(afr, bfr0, acc[0], 0, 0, 0);
      acc[1] = __builtin_amdgcn_mfma_f32_16x16x32_bf16(afr, bfr1, acc[1], 0, 0, 0);
    }
#pragma unroll
    for (int nj = 0; nj < 2; nj++) {
      int col = wid * 32 + nj * 16 + lr;
      float bv = b1[col];
#pragma unroll
      for (int r = 0; r < 4; r++)
        a1[(lq * 4 + r) * AP + col] = f2bf(fmaxf(acc[nj][r] + bv, 0.f));
    }
  }
  __syncthreads();   // B1: a1 visible, zh dead

  // ---- GEMM2: a2 = relu(a1 @ W2 + b2)  (a2 aliases zh; B1 separates)
  {
    f32x4 acc[2] = {};
#pragma unroll
    for (int kt = 0; kt < 4; kt++) {
      bf16x8 afr = *(const bf16x8*)&a1[lr * AP + kt * 32 + lq * 8];
      bf16x8 bfr0 = *(const bf16x8*)&wp[W2P_OFF + ((wid * 2 + 0) * 4 + kt) * 64 + l];
      bf16x8 bfr1 = *(const bf16x8*)&wp[W2P_OFF + ((wid * 2 + 1) * 4 + kt) * 64 + l];
      acc[0] = __builtin_amdgcn_mfma_f32_16x16x32_bf16(afr, bfr0, acc[0], 0, 0, 0);
      acc[1] = __builtin_amdgcn_mfma_f32_16x16x32_bf16(afr, bfr1, acc[1], 0, 0, 0);
    }
#pragma unroll
    for (int nj = 0; nj < 2; nj++) {
      int col = wid * 32 + nj * 16 + lr;
      float bv = b2[col];
#pragma unroll
      for (int r = 0; r < 4; r++)
        a2[(lq * 4 + r) * AP + col] = f2bf(fmaxf(acc[nj][r] + bv, 0.f));
    }
  }
  __syncthreads();   // B2: a2 visible

  // ---- GEMM3: st = a2 @ W3 + b3 ; wave owns s-cols [32w,32w+32), t-cols +128
  f32x4 acc3[4] = {};
#pragma unroll
  for (int kt = 0; kt < 4; kt++) {
    bf16x8 afr = *(const bf16x8*)&a2[lr * AP + kt * 32 + lq * 8];
    bf16x8 bfrS0 = *(const bf16x8*)&wp[W3P_OFF + ((wid * 2 + 0) * 4 + kt) * 64 + l];
    bf16x8 bfrS1 = *(const bf16x8*)&wp[W3P_OFF + ((wid * 2 + 1) * 4 + kt) * 64 + l];
    bf16x8 bfrT0 = *(const bf16x8*)&wp[W3P_OFF + ((8 + wid * 2 + 0) * 4 + kt) * 64 + l];
    bf16x8 bfrT1 = *(const bf16x8*)&wp[W3P_OFF + ((8 + wid * 2 + 1) * 4 + kt) * 64 + l];
    acc3[0] = __builtin_amdgcn_mfma_f32_16x16x32_bf16(afr, bfrS0, acc3[0], 0, 0, 0);
    acc3[1] = __builtin_amdgcn_mfma_f32_16x16x32_bf16(afr, bfrS1, acc3[1], 0, 0, 0);
    acc3[2] = __builtin_amdgcn_mfma_f32_16x16x32_bf16(afr, bfrT0, acc3[2], 0, 0, 0);
    acc3[3] = __builtin_amdgcn_mfma_f32_16x16x32_bf16(afr, bfrT1, acc3[3], 0, 0, 0);
  }

  // ---- epilogue: x pair from LDS (exact f32), tanh/exp, y write, log_det
  float lp[4] = {0.f, 0.f, 0.f, 0.f};
#pragma unroll
  for (int nj = 0; nj < 2; nj++) {
    int colc = wid * 32 + nj * 16 + lr;   // 0..127
    float bs = b3[colc];
    float bt = b3[128 + colc];
#pragma unroll
    for (int r = 0; r < 4; r++) {
      int lrow = lq * 4 + r;
      float sv = tanh_fast(acc3[nj][r] + bs);
      float tv = acc3[nj + 2][r] + bt;
      lp[r] += sv;
      const float2 xv = *(const float2*)&xs[lrow * XP + 2 * colc];  // {x_even, x_odd}
      float2 o;
      o.x = xv.x;                            // exact pass-through
      o.y = xv.y * __expf(sv) + tv;
      *(float2*)(y + (size_t)(m0 + lrow) * 256 + 2 * colc) = o;
    }
  }

  // log_det: reduce 16 lanes (col dim, 32 cols/wave) then combine 4 waves
#pragma unroll
  for (int r = 0; r < 4; r++) {
    float v = lp[r];
    v += __shfl_xor(v, 1);
    v += __shfl_xor(v, 2);
    v += __shfl_xor(v, 4);
    v += __shfl_xor(v, 8);
    if (lr == 0) lsum[wid * BM + lq * 4 + r] = v;
  }
  __syncthreads();   // B3
  if (t < BM)
    ldet[m0 + t] = lsum[t] + lsum[BM + t] + lsum[2 * BM + t] + lsum[3 * BM + t];
}

extern "C" void kernel_launch(void* const* d_in, const int* in_sizes, int n_in,
                              void* d_out, int out_size, void* d_ws, size_t ws_size,
                              hipStream_t stream) {
  const float* x  = (const float*)d_in[0];
  const float* h  = (const float*)d_in[1];
  const float* W1 = (const float*)d_in[2];
  const float* b1 = (const float*)d_in[3];
  const float* W2 = (const float*)d_in[4];
  const float* b2 = (const float*)d_in[5];
  const float* W3 = (const float*)d_in[6];
  const float* b3 = (const float*)d_in[7];
  float* y    = (float*)d_out;
  float* ldet = y + (size_t)B_ROWS * 256;
  uint4* wp   = (uint4*)d_ws;

  prepack_kernel<<<52, 256, 0, stream>>>(W1, W2, W3, wp);

  (void)hipFuncSetAttribute((const void*)fused_kernel,
                            hipFuncAttributeMaxDynamicSharedMemorySize, LDS_TOTAL);
  fused_kernel<<<B_ROWS / BM, 256, LDS_TOTAL, stream>>>(x, h, b1, b2, b3, wp, y, ldet);
}